// Round 7
// baseline (2437.716 us; speedup 1.0000x reference)
//
#include <hip/hip_runtime.h>

// Problem constants
#define KN 1024      // num_embeddings
#define DD 256       // embedding_dim
#define NTOT 32768   // 32*32*32 flattened rows
#define HW 1024      // 32*32 spatial per batch

// Output layout (flat f32, concatenated in return order)
#define OFF_LOSS 0
#define OFF_ZQ   1
#define OFF_PERP 8388609
#define OFF_EMB  8388610
#define OFF_IND  41943042

// ws layout:
// [0,8)              double lossSum
// [8,4104)           uint cnt[1024]
// [4112,8208)        float wsum2[1024]
// [8208,8208+512K)   ushort wBh  (bf16 hi of w, fragment-linear, see vq_prep)
#define WS_WSUM2_OFF 4112
#define WS_WBH_OFF   8208

#define XS_STRIDE 260          // f32 row stride for x tile (16B-aligned rows)

typedef __bf16 bf16x8 __attribute__((ext_vector_type(8)));
typedef float  f32x4  __attribute__((ext_vector_type(4)));
typedef float  f32x2  __attribute__((ext_vector_type(2)));
typedef unsigned short ushort_t;

// ---- dynamic LDS layout (bytes), 16-row tile, 30.6 KB -> 2-3 blocks/CU ----
#define SM_XS    0            // f32 [16][260]
#define SM_XFH   16640        // ushort [8s][64lane][8]
#define SM_WSC   24832        // f32 [1024]
#define SM_PART  28928        // f32 [16][17] (dead after asum phase)
#define SM_REDV  28928        // f32 [8wave][16row] (overlay, post-MFMA)
#define SM_ROWM  30016        // f32 [16]  (rowmin + per-row THR)
#define SM_CCNT  30080        // uint [16]
#define SM_CLIST 30144        // int  [16][8]
#define SM_FV    30656        // f32  [16][8]
#define SM_ASUM  31168        // f32  [16]
#define SM_BI    31232        // int  [16]
#define SM_LRED  31296        // dbl  [4]
#define SM_SIZE  31328

__device__ __forceinline__ unsigned short bf16_rne(float f) {
    unsigned u = __float_as_uint(f);
    return (unsigned short)((u + 0x7FFFu + ((u >> 16) & 1u)) >> 16);
}

// exact reference-order distance: fmaf chain in ascending d, then (a - 2*dot) + c
__device__ __forceinline__ float exact_dist(const float* xs, const float* wsC,
                                            const float* asum,
                                            const float* __restrict__ w,
                                            int r, int k) {
    float a = 0.f;
    const float4* wr = (const float4*)(w + k * DD);
    const float4* xr = (const float4*)(xs + r * XS_STRIDE);
    #pragma unroll 4
    for (int q = 0; q < 64; ++q) {
        const float4 wv = wr[q];
        const float4 xv = xr[q];
        a = fmaf(xv.x, wv.x, a);
        a = fmaf(xv.y, wv.y, a);
        a = fmaf(xv.z, wv.z, a);
        a = fmaf(xv.w, wv.w, a);
    }
    return (asum[r] - 2.0f * a) + wsC[k];
}

__global__ __launch_bounds__(256) void vq_prep(const float* __restrict__ w,
                                               float* __restrict__ wsum2,
                                               ushort_t* __restrict__ wBh) {
    const int k = blockIdx.x;
    const int d = threadIdx.x;
    float v = w[k * DD + d];
    {
        // fragment-linear scatter: frag for (coltile c, kstep s), lane = (k&15)|(g<<4),
        // elem j holds w[k][s*32 + g*8 + j]  (same kappa map as A-frags -> HW k-map cancels)
        const int c = k >> 4, s0 = d >> 5, g = (d >> 3) & 3, j = d & 7;
        const int lane = (k & 15) | (g << 4);
        const int idx = (((c * 8 + s0) * 64 + lane) << 3) + j;
        wBh[idx] = bf16_rne(v);
    }
    // wsum2: identical to previous (bit-exact) version
    float s = v * v;
    #pragma unroll
    for (int off = 32; off; off >>= 1) s += __shfl_down(s, off, 64);
    __shared__ float wsum[4];
    const int wave = d >> 6, lane = d & 63;
    if (lane == 0) wsum[wave] = s;
    __syncthreads();
    if (d == 0) wsum2[k] = (wsum[0] + wsum[1]) + (wsum[2] + wsum[3]);
}

__global__ __launch_bounds__(512, 4) void vq_main(const float* __restrict__ lat,
                                                  const float* __restrict__ w,
                                                  const float* __restrict__ wsum2,
                                                  const ushort_t* __restrict__ wBh,
                                                  float* __restrict__ out,
                                                  unsigned* __restrict__ cnt,
                                                  double* __restrict__ lossSum) {
    extern __shared__ char smem[];
    float*    xs    = (float*)(smem + SM_XS);
    ushort_t* xfH   = (ushort_t*)(smem + SM_XFH);
    float*    wsC   = (float*)(smem + SM_WSC);
    float*    part  = (float*)(smem + SM_PART);
    float*    redv  = (float*)(smem + SM_REDV);
    float*    rowm  = (float*)(smem + SM_ROWM);
    unsigned* ccnt  = (unsigned*)(smem + SM_CCNT);
    int*      clist = (int*)(smem + SM_CLIST);
    float*    fv    = (float*)(smem + SM_FV);
    float*    asum  = (float*)(smem + SM_ASUM);
    int*      bi    = (int*)(smem + SM_BI);
    double*   lred  = (double*)(smem + SM_LRED);

    const int n0  = blockIdx.x * 16;          // 16 rows per block
    const int b   = n0 >> 10;                 // batch index
    const int hw0 = n0 & 1023;                // spatial offset (multiple of 16)
    const int tid = threadIdx.x;              // 0..511, 8 waves
    const int l   = tid & 63;
    const int wv  = tid >> 6;

    // ---- Stage latents: NCHW gather -> LDS [row][d] (f32x4, nontemporal) ----
    {
        const float* base = lat + (size_t)b * (DD * HW) + hw0;
        #pragma unroll
        for (int it = 0; it < 2; ++it) {
            const int u = it * 512 + tid;         // 0..1023 float4 units
            const int d = u >> 2, r4 = (u & 3) * 4;
            const f32x4 v = __builtin_nontemporal_load(
                reinterpret_cast<const f32x4*>(base + d * HW + r4));
            xs[(r4 + 0) * XS_STRIDE + d] = v.x;
            xs[(r4 + 1) * XS_STRIDE + d] = v.y;
            xs[(r4 + 2) * XS_STRIDE + d] = v.z;
            xs[(r4 + 3) * XS_STRIDE + d] = v.w;
        }
        wsC[tid] = wsum2[tid];
        wsC[tid + 512] = wsum2[tid + 512];
    }
    __syncthreads();

    // ---- A[r] = sum_d x^2 (bit-exact replica of the 256-thread structure) ----
    if (tid < 256) {
        const int r = tid & 15, seg = tid >> 4;
        float p = 0.f;
        #pragma unroll
        for (int i = 0; i < 16; ++i) {
            float x = xs[r * XS_STRIDE + seg * 16 + i];
            p += x * x;
        }
        part[seg * 17 + r] = p;
    }
    __syncthreads();
    if (tid < 16) {
        float a = 0.f;
        #pragma unroll
        for (int s = 0; s < 16; ++s) a += part[s * 17 + tid];
        asum[tid] = a;
    }
    __syncthreads();

    // ---- Build bf16 hi A-fragments (lane-linear in LDS), 1 unit/thread ----
    {
        const int u  = tid;                           // 0..511 fragment units
        const int s0 = u >> 6, ll = u & 63;
        const int row = ll & 15;
        const int d0  = s0 * 32 + (ll >> 4) * 8;
        const float4 x0 = *(const float4*)(xs + row * XS_STRIDE + d0);
        const float4 x1 = *(const float4*)(xs + row * XS_STRIDE + d0 + 4);
        float xv[8] = {x0.x, x0.y, x0.z, x0.w, x1.x, x1.y, x1.z, x1.w};
        unsigned hh[8];
        #pragma unroll
        for (int j = 0; j < 8; ++j) hh[j] = bf16_rne(xv[j]);
        uint4 ph;
        ph.x = hh[0] | (hh[1] << 16); ph.y = hh[2] | (hh[3] << 16);
        ph.z = hh[4] | (hh[5] << 16); ph.w = hh[6] | (hh[7] << 16);
        *(uint4*)(xfH + u * 8) = ph;
    }
    __syncthreads();

    // ---- MFMA GEMM: single bf16 pass, per-wave 128 cols, named 2-deep prefetch ----
    f32x4 acc[8];
    #pragma unroll
    for (int c = 0; c < 8; ++c) acc[c] = (f32x4){0.f, 0.f, 0.f, 0.f};

    {
        bf16x8 ah, pb0, pb1;                   // NAMED regs only (rule #20)
        #define BOFF(s0_, c_) (((size_t)(((wv * 8 + (c_)) * 8 + (s0_)) * 64 + l)) * 8)
        pb0 = *(const bf16x8*)(wBh + BOFF(0, 0));
        pb1 = *(const bf16x8*)(wBh + BOFF(0, 1));

        #pragma unroll
        for (int s0 = 0; s0 < 8; ++s0) {
            ah = *(const bf16x8*)(xfH + (s0 * 64 + l) * 8);
            #pragma unroll
            for (int c = 0; c < 8; ++c) {
                const bf16x8 bh = (c & 1) ? pb1 : pb0;
                const int nit = s0 * 8 + c + 2;
                if (nit < 64) {
                    const int ns = nit >> 3, nc = nit & 7;
                    if (c & 1) pb1 = *(const bf16x8*)(wBh + BOFF(ns, nc));
                    else       pb0 = *(const bf16x8*)(wBh + BOFF(ns, nc));
                }
                acc[c] = __builtin_amdgcn_mfma_f32_16x16x32_bf16(ah, bh, acc[c], 0, 0, 0);
            }
        }
        #undef BOFF
    }

    // ---- d' = C - 2*acc (A dropped: constant per row); per-lane running min ----
    float rmv[4];
    #pragma unroll
    for (int q = 0; q < 4; ++q) rmv[q] = 3.4e38f;
    #pragma unroll
    for (int c = 0; c < 8; ++c) {
        const float cv = wsC[(wv * 8 + c) * 16 + (l & 15)];
        #pragma unroll
        for (int q = 0; q < 4; ++q) {
            const float dv = fmaf(-2.0f, acc[c][q], cv);
            acc[c][q] = dv;
            rmv[q] = fminf(rmv[q], dv);
        }
    }
    // reduce min across the 16 lanes sharing rows (same l>>4 group)
    #pragma unroll
    for (int q = 0; q < 4; ++q) {
        float m = rmv[q];
        #pragma unroll
        for (int off = 1; off < 16; off <<= 1) m = fminf(m, __shfl_xor(m, off, 64));
        rmv[q] = m;
    }
    if ((l & 15) == 0) {
        const int g = l >> 4;
        #pragma unroll
        for (int q = 0; q < 4; ++q)
            redv[wv * 16 + g * 4 + q] = rmv[q];
    }
    __syncthreads();
    // rowm[r] <- rowmin + THR_r.  Rigorous single-bf16 bound:
    //   |dist_err| <= 2*2*2^-9*|x|*|w|max <= 1.22e-4*sqrt(asum); use 2x + cushion
    if (tid < 16) {
        float m = redv[tid];
        #pragma unroll
        for (int ww = 1; ww < 8; ++ww) m = fminf(m, redv[ww * 16 + tid]);
        rowm[tid] = m + fmaf(2.5e-4f, sqrtf(asum[tid]), 1.2e-4f);
        ccnt[tid] = 0u;
    }
    __syncthreads();

    // ---- candidate collection: all k with d' <= rowmin + THR_r ----
    #pragma unroll
    for (int q = 0; q < 4; ++q) {
        const int row = ((l >> 4) << 2) + q;
        const float lim = rowm[row];
        #pragma unroll
        for (int c = 0; c < 8; ++c) {
            if (acc[c][q] <= lim) {
                const unsigned pos = atomicAdd(&ccnt[row], 1u);
                if (pos < 8) clist[row * 8 + pos] = (wv * 8 + c) * 16 + (l & 15);
            }
        }
    }
    __syncthreads();

    // ---- exact fallback for rows with >=2 candidates (ref fl order) ----
    if (tid < 128) {
        const int r = tid >> 3, ci = tid & 7;
        const unsigned cc = ccnt[r];
        if (cc >= 2u) {
            if (cc <= 8u) {
                if ((unsigned)ci < cc)
                    fv[r * 8 + ci] = exact_dist(xs, wsC, asum, w, r, clist[r * 8 + ci]);
            } else if (ci == 0) {
                // rare safety net: full exact scan, first-min (== tie -> lowest k)
                float bvv = 3.4e38f; int bkk = 0;
                for (int k = 0; k < KN; ++k) {
                    const float dvv = exact_dist(xs, wsC, asum, w, r, k);
                    if (dvv < bvv) { bvv = dvv; bkk = k; }
                }
                bi[r] = bkk;
            }
        }
    }
    __syncthreads();
    if (tid < 16) {
        const unsigned cc = ccnt[tid];
        int kk;
        if (cc == 1u) kk = clist[tid * 8];
        else if (cc <= 8u) {
            float v = fv[tid * 8]; kk = clist[tid * 8];
            for (unsigned ci = 1; ci < cc; ++ci) {
                const float ov = fv[tid * 8 + ci];
                const int   ok = clist[tid * 8 + ci];
                if (ov < v || (ov == v && ok < kk)) { v = ov; kk = ok; }
            }
        } else kk = bi[tid];
        bi[tid] = kk;
        __builtin_nontemporal_store((float)kk, &out[OFF_IND + n0 + tid]);
        atomicAdd(&cnt[kk], 1u);
    }
    __syncthreads();

    // ---- z_q straight-through: f32x2 stores (8B aligned; hw0 mult of 16) ----
    {
        float* zq_out = out + OFF_ZQ + (size_t)b * (DD * HW) + hw0;
        #pragma unroll
        for (int it = 0; it < 4; ++it) {
            const int u = it * 512 + tid;     // 0..2047 f32x2 units: 256 d x 8 pairs
            const int d = u >> 3, j2 = (u & 7) * 2;
            const float la0 = xs[(j2 + 0) * XS_STRIDE + d];
            const float la1 = xs[(j2 + 1) * XS_STRIDE + d];
            const float z0  = w[bi[j2 + 0] * DD + d];
            const float z1  = w[bi[j2 + 1] * DD + d];
            f32x2 v;
            v.x = la0 + (z0 - la0);           // fl(lat + fl(zq - lat))
            v.y = la1 + (z1 - la1);
            __builtin_nontemporal_store(v, reinterpret_cast<f32x2*>(zq_out + d * HW + j2));
        }
    }

    // ---- min_embed one-hot rows (nontemporal f32x2; OFF_EMB only 8B-aligned) ----
    {
        f32x2* emb2 = reinterpret_cast<f32x2*>(out + OFF_EMB) + (size_t)n0 * (KN / 2);
        #pragma unroll
        for (int it = 0; it < 16; ++it) {
            const int f = it * 512 + tid;     // [0, 8192) float2 slots
            const int r = f >> 9;             // 512 float2 per row
            const int kq = (f & 511) * 2;
            const int tt = bi[r];
            f32x2 v2;
            v2.x = (kq     == tt) ? 1.0f : 0.0f;
            v2.y = (kq + 1 == tt) ? 1.0f : 0.0f;
            __builtin_nontemporal_store(v2, &emb2[f]);
        }
    }

    // ---- loss: bit-exact 256-thread replica (store-free; same dif bits) ----
    if (tid < 256) {
        const int jj = tid & 15, db = tid >> 4;
        const int krow = bi[jj];
        float lsum = 0.f;
        #pragma unroll
        for (int it = 0; it < 16; ++it) {
            const int d = it * 16 + db;
            const float latv = xs[jj * XS_STRIDE + d];
            const float zq   = w[krow * DD + d];
            const float dif  = zq - latv;            // fl(zq - lat)
            lsum = fmaf(dif, dif, lsum);
        }
        float s2 = lsum;
        #pragma unroll
        for (int off = 32; off; off >>= 1) s2 += __shfl_down(s2, off, 64);
        if ((tid & 63) == 0) lred[wv] = (double)s2;
    }
    __syncthreads();
    if (tid == 0) {
        double t = (lred[0] + lred[1]) + (lred[2] + lred[3]);
        atomicAdd(lossSum, t);
    }
}

__global__ __launch_bounds__(1024) void vq_finalize(const unsigned* __restrict__ cnt,
                                                    const double* __restrict__ lossSum,
                                                    float* __restrict__ out) {
    const int t = threadIdx.x;
    __shared__ float red[16];
    const float e = (float)cnt[t] * (1.0f / 32768.0f);
    float s = e * logf(e + 1e-10f);
    #pragma unroll
    for (int off = 32; off; off >>= 1) s += __shfl_down(s, off, 64);
    const int wave = t >> 6, lane = t & 63;
    if (lane == 0) red[wave] = s;
    __syncthreads();
    if (t == 0) {
        float tot = 0.f;
        #pragma unroll
        for (int i = 0; i < 16; ++i) tot += red[i];
        out[OFF_PERP] = expf(-tot);
        const float m = (float)(lossSum[0] * (1.0 / 8388608.0));
        out[OFF_LOSS] = m + 0.25f * m;   // matches fl(m1 + fl(0.25*m2)), m1==m2
    }
}

extern "C" void kernel_launch(void* const* d_in, const int* in_sizes, int n_in,
                              void* d_out, int out_size, void* d_ws, size_t ws_size,
                              hipStream_t stream) {
    const float* lat = (const float*)d_in[0];   // [32,256,32,32] f32 NCHW
    const float* w   = (const float*)d_in[1];   // [1024,256] f32

    char* ws = (char*)d_ws;
    double*   lossSum = (double*)ws;
    unsigned* cnt     = (unsigned*)(ws + 8);
    float*    wsum2   = (float*)(ws + WS_WSUM2_OFF);
    ushort_t* wBh     = (ushort_t*)(ws + WS_WBH_OFF);
    float*    out     = (float*)d_out;

    // zero loss accumulator + histogram every call (we accumulate into them)
    (void)hipMemsetAsync(d_ws, 0, 4104, stream);

    vq_prep<<<KN, 256, 0, stream>>>(w, wsum2, wBh);
    vq_main<<<NTOT / 16, 512, SM_SIZE, stream>>>(lat, w, wsum2, wBh, out, cnt, lossSum);
    vq_finalize<<<1, 1024, 0, stream>>>(cnt, lossSum, out);
}

// Round 8
// 129.457 us; speedup vs baseline: 18.8304x; 18.8304x over previous
//
#include <hip/hip_runtime.h>

// Problem constants
#define KN 1024      // num_embeddings
#define DD 256       // embedding_dim
#define NTOT 32768   // 32*32*32 flattened rows
#define HW 1024      // 32*32 spatial per batch

// Output layout (flat f32, concatenated in return order)
#define OFF_LOSS 0
#define OFF_ZQ   1
#define OFF_PERP 8388609
#define OFF_EMB  8388610
#define OFF_IND  41943042

// ws layout:
// [0,8)              double lossSum
// [8,4104)           uint cnt[1024]
// [4112,8208)        float wsum2[1024]
// [8208,8208+512K)   ushort wBh  (bf16 hi of w, fragment-linear, see vq_prep)
// [+512K,+1M)        ushort wBl  (bf16 lo of w)
#define WS_WSUM2_OFF 4112
#define WS_WBH_OFF   8208
#define WS_WBL_OFF   (8208 + 524288)

#define XS_STRIDE 260          // f32 row stride for x tile (16B-aligned rows)
#define THR 3.0e-4f            // candidate margin; >= 2x hi/lo error bound (R1-R4 proven)

typedef __bf16 bf16x8 __attribute__((ext_vector_type(8)));
typedef float  f32x4  __attribute__((ext_vector_type(4)));
typedef float  f32x2  __attribute__((ext_vector_type(2)));
typedef unsigned short ushort_t;

// ---- dynamic LDS layout (bytes), 32-row tile, 73.8 KB -> 2 blocks/CU (147.6 < 160) ----
#define SM_XS    0            // f32 [32][260]
#define SM_XFH   33280        // ushort [2rt][8s][64lane][8]
#define SM_XFL   49664        // ushort [2rt][8s][64lane][8]
#define SM_WSC   66048        // f32 [1024]
#define SM_PART  70144        // f32 [16][17] (dead after asum phase)
#define SM_REDV  70144        // f32 [8wave][32row] (overlay, post-MFMA)
#define SM_ROWM  71232        // f32 [32]
#define SM_CCNT  71360        // uint [32]
#define SM_CLIST 71488        // int  [32][8]
#define SM_FV    72512        // f32  [32][8]
#define SM_ASUM  73536        // f32  [32]
#define SM_BI    73664        // int  [32]
#define SM_LRED  73792        // dbl  [4]
#define SM_SIZE  73824

__device__ __forceinline__ unsigned short bf16_rne(float f) {
    unsigned u = __float_as_uint(f);
    return (unsigned short)((u + 0x7FFFu + ((u >> 16) & 1u)) >> 16);
}

// exact reference-order distance: fmaf chain in ascending d, then (a - 2*dot) + c
__device__ __forceinline__ float exact_dist(const float* xs, const float* wsC,
                                            const float* asum,
                                            const float* __restrict__ w,
                                            int r, int k) {
    float a = 0.f;
    const float4* wr = (const float4*)(w + k * DD);
    const float4* xr = (const float4*)(xs + r * XS_STRIDE);
    #pragma unroll 4
    for (int q = 0; q < 64; ++q) {
        const float4 wv = wr[q];
        const float4 xv = xr[q];
        a = fmaf(xv.x, wv.x, a);
        a = fmaf(xv.y, wv.y, a);
        a = fmaf(xv.z, wv.z, a);
        a = fmaf(xv.w, wv.w, a);
    }
    return (asum[r] - 2.0f * a) + wsC[k];
}

__global__ __launch_bounds__(256) void vq_prep(const float* __restrict__ w,
                                               float* __restrict__ wsum2,
                                               ushort_t* __restrict__ wBh,
                                               ushort_t* __restrict__ wBl) {
    const int k = blockIdx.x;
    const int d = threadIdx.x;
    float v = w[k * DD + d];
    {
        // fragment-linear scatter: frag for (coltile c, kstep s), lane = (k&15)|(g<<4),
        // elem j holds w[k][s*32 + g*8 + j]  (same kappa map as A-frags -> HW k-map cancels)
        const int c = k >> 4, s0 = d >> 5, g = (d >> 3) & 3, j = d & 7;
        const int lane = (k & 15) | (g << 4);
        const int idx = (((c * 8 + s0) * 64 + lane) << 3) + j;
        const unsigned short hh = bf16_rne(v);
        wBh[idx] = hh;
        wBl[idx] = bf16_rne(v - __uint_as_float((unsigned)hh << 16));
    }
    // wsum2: identical to previous (bit-exact) version
    float s = v * v;
    #pragma unroll
    for (int off = 32; off; off >>= 1) s += __shfl_down(s, off, 64);
    __shared__ float wsum[4];
    const int wave = d >> 6, lane = d & 63;
    if (lane == 0) wsum[wave] = s;
    __syncthreads();
    if (d == 0) wsum2[k] = (wsum[0] + wsum[1]) + (wsum[2] + wsum[3]);
}

__global__ __launch_bounds__(512, 4) void vq_main(const float* __restrict__ lat,
                                                  const float* __restrict__ w,
                                                  const float* __restrict__ wsum2,
                                                  const ushort_t* __restrict__ wBh,
                                                  const ushort_t* __restrict__ wBl,
                                                  float* __restrict__ out,
                                                  unsigned* __restrict__ cnt,
                                                  double* __restrict__ lossSum) {
    extern __shared__ char smem[];
    float*    xs    = (float*)(smem + SM_XS);
    ushort_t* xfH   = (ushort_t*)(smem + SM_XFH);
    ushort_t* xfL   = (ushort_t*)(smem + SM_XFL);
    float*    wsC   = (float*)(smem + SM_WSC);
    float*    part  = (float*)(smem + SM_PART);
    float*    redv  = (float*)(smem + SM_REDV);
    float*    rowm  = (float*)(smem + SM_ROWM);
    unsigned* ccnt  = (unsigned*)(smem + SM_CCNT);
    int*      clist = (int*)(smem + SM_CLIST);
    float*    fv    = (float*)(smem + SM_FV);
    float*    asum  = (float*)(smem + SM_ASUM);
    int*      bi    = (int*)(smem + SM_BI);
    double*   lred  = (double*)(smem + SM_LRED);

    const int n0  = blockIdx.x * 32;          // 32 rows per block
    const int b   = n0 >> 10;                 // batch index
    const int hw0 = n0 & 1023;                // spatial offset (multiple of 32)
    const int tid = threadIdx.x;              // 0..511, 8 waves
    const int l   = tid & 63;
    const int wv  = tid >> 6;

    // ---- Stage latents: NCHW gather -> LDS [row][d] (f32x4, nontemporal) ----
    {
        const float* base = lat + (size_t)b * (DD * HW) + hw0;
        #pragma unroll
        for (int it = 0; it < 4; ++it) {
            const int u = it * 512 + tid;         // 0..2047 float4 units: 256 d x 8
            const int d = u >> 3, r4 = (u & 7) * 4;
            const f32x4 v = __builtin_nontemporal_load(
                reinterpret_cast<const f32x4*>(base + d * HW + r4));
            xs[(r4 + 0) * XS_STRIDE + d] = v.x;
            xs[(r4 + 1) * XS_STRIDE + d] = v.y;
            xs[(r4 + 2) * XS_STRIDE + d] = v.z;
            xs[(r4 + 3) * XS_STRIDE + d] = v.w;
        }
        wsC[tid] = wsum2[tid];
        wsC[tid + 512] = wsum2[tid + 512];
    }
    __syncthreads();

    // ---- A[r] = sum_d x^2 (bit-exact replica of the 256-thread structure) ----
    #pragma unroll
    for (int h = 0; h < 2; ++h) {
        if (tid < 256) {
            const int r = tid & 15, seg = tid >> 4;
            float p = 0.f;
            #pragma unroll
            for (int i = 0; i < 16; ++i) {
                float x = xs[(h * 16 + r) * XS_STRIDE + seg * 16 + i];
                p += x * x;
            }
            part[seg * 17 + r] = p;
        }
        __syncthreads();
        if (tid < 16) {
            float a = 0.f;
            #pragma unroll
            for (int s = 0; s < 16; ++s) a += part[s * 17 + tid];
            asum[h * 16 + tid] = a;
        }
        __syncthreads();
    }

    // ---- Build bf16 hi/lo A-fragments (lane-linear in LDS), 2 units/thread ----
    #pragma unroll
    for (int i = 0; i < 2; ++i) {
        const int u  = tid + i * 512;                 // 0..1023 fragment units
        const int rt = u >> 9, s0 = (u >> 6) & 7, ll = u & 63;
        const int row = rt * 16 + (ll & 15);
        const int d0  = s0 * 32 + (ll >> 4) * 8;
        const float4 x0 = *(const float4*)(xs + row * XS_STRIDE + d0);
        const float4 x1 = *(const float4*)(xs + row * XS_STRIDE + d0 + 4);
        float xv[8] = {x0.x, x0.y, x0.z, x0.w, x1.x, x1.y, x1.z, x1.w};
        unsigned hh[8], lo[8];
        #pragma unroll
        for (int j = 0; j < 8; ++j) {
            hh[j] = bf16_rne(xv[j]);
            lo[j] = bf16_rne(xv[j] - __uint_as_float(hh[j] << 16));
        }
        uint4 ph, pl;
        ph.x = hh[0] | (hh[1] << 16); ph.y = hh[2] | (hh[3] << 16);
        ph.z = hh[4] | (hh[5] << 16); ph.w = hh[6] | (hh[7] << 16);
        pl.x = lo[0] | (lo[1] << 16); pl.y = lo[2] | (lo[3] << 16);
        pl.z = lo[4] | (lo[5] << 16); pl.w = lo[6] | (lo[7] << 16);
        *(uint4*)(xfH + u * 8) = ph;
        *(uint4*)(xfL + u * 8) = pl;
    }
    __syncthreads();

    // ---- MFMA GEMM: hi/lo 3-product, per-wave 128 cols, named 2-deep prefetch ----
    // (R2's proven core: VGPR=76, clean codegen)
    f32x4 acc[2][8];
    #pragma unroll
    for (int rt = 0; rt < 2; ++rt)
        #pragma unroll
        for (int c = 0; c < 8; ++c)
            acc[rt][c] = (f32x4){0.f, 0.f, 0.f, 0.f};

    {
        bf16x8 ah0, ah1, al0, al1;
        bf16x8 pbh0, pbl0, pbh1, pbl1;       // 2-slot pipeline (named -> regs)

        #define BOFF(s0_, c_) (((size_t)(((wv * 8 + (c_)) * 8 + (s0_)) * 64 + l)) * 8)
        pbh0 = *(const bf16x8*)(wBh + BOFF(0, 0));
        pbl0 = *(const bf16x8*)(wBl + BOFF(0, 0));
        pbh1 = *(const bf16x8*)(wBh + BOFF(0, 1));
        pbl1 = *(const bf16x8*)(wBl + BOFF(0, 1));

        #pragma unroll
        for (int it = 0; it < 64; ++it) {
            const int s0 = it >> 3, c = it & 7;
            if (c == 0) {
                ah0 = *(const bf16x8*)(xfH + ((0 * 8 + s0) * 64 + l) * 8);
                ah1 = *(const bf16x8*)(xfH + ((1 * 8 + s0) * 64 + l) * 8);
                al0 = *(const bf16x8*)(xfL + ((0 * 8 + s0) * 64 + l) * 8);
                al1 = *(const bf16x8*)(xfL + ((1 * 8 + s0) * 64 + l) * 8);
            }
            bf16x8 bh, bl;
            if ((it & 1) == 0) { bh = pbh0; bl = pbl0; } else { bh = pbh1; bl = pbl1; }
            if (it + 2 < 64) {
                const int nit = it + 2, ns = nit >> 3, nc = nit & 7;
                if ((it & 1) == 0) {
                    pbh0 = *(const bf16x8*)(wBh + BOFF(ns, nc));
                    pbl0 = *(const bf16x8*)(wBl + BOFF(ns, nc));
                } else {
                    pbh1 = *(const bf16x8*)(wBh + BOFF(ns, nc));
                    pbl1 = *(const bf16x8*)(wBl + BOFF(ns, nc));
                }
            }
            acc[0][c] = __builtin_amdgcn_mfma_f32_16x16x32_bf16(ah0, bh, acc[0][c], 0, 0, 0);
            acc[1][c] = __builtin_amdgcn_mfma_f32_16x16x32_bf16(ah1, bh, acc[1][c], 0, 0, 0);
            acc[0][c] = __builtin_amdgcn_mfma_f32_16x16x32_bf16(ah0, bl, acc[0][c], 0, 0, 0);
            acc[1][c] = __builtin_amdgcn_mfma_f32_16x16x32_bf16(ah1, bl, acc[1][c], 0, 0, 0);
            acc[0][c] = __builtin_amdgcn_mfma_f32_16x16x32_bf16(al0, bh, acc[0][c], 0, 0, 0);
            acc[1][c] = __builtin_amdgcn_mfma_f32_16x16x32_bf16(al1, bh, acc[1][c], 0, 0, 0);
        }
        #undef BOFF
    }

    // ---- d' = C - 2*acc (A dropped: constant per row); per-lane running min ----
    float rmv[2][4];
    #pragma unroll
    for (int rt = 0; rt < 2; ++rt)
        #pragma unroll
        for (int q = 0; q < 4; ++q) rmv[rt][q] = 3.4e38f;
    #pragma unroll
    for (int c = 0; c < 8; ++c) {
        const float cv = wsC[(wv * 8 + c) * 16 + (l & 15)];
        #pragma unroll
        for (int rt = 0; rt < 2; ++rt) {
            #pragma unroll
            for (int q = 0; q < 4; ++q) {
                const float dv = fmaf(-2.0f, acc[rt][c][q], cv);
                acc[rt][c][q] = dv;
                rmv[rt][q] = fminf(rmv[rt][q], dv);
            }
        }
    }
    #pragma unroll
    for (int rt = 0; rt < 2; ++rt)
        #pragma unroll
        for (int q = 0; q < 4; ++q) {
            float m = rmv[rt][q];
            #pragma unroll
            for (int off = 1; off < 16; off <<= 1) m = fminf(m, __shfl_xor(m, off, 64));
            rmv[rt][q] = m;
        }
    if ((l & 15) == 0) {
        const int g = l >> 4;
        #pragma unroll
        for (int rt = 0; rt < 2; ++rt)
            #pragma unroll
            for (int q = 0; q < 4; ++q)
                redv[wv * 32 + rt * 16 + g * 4 + q] = rmv[rt][q];
    }
    __syncthreads();
    if (tid < 32) {
        float m = redv[tid];
        #pragma unroll
        for (int ww = 1; ww < 8; ++ww) m = fminf(m, redv[ww * 32 + tid]);
        rowm[tid] = m;
        ccnt[tid] = 0u;
    }
    __syncthreads();

    // ---- candidate collection: all k with d' <= rowmin + THR ----
    #pragma unroll
    for (int rt = 0; rt < 2; ++rt) {
        #pragma unroll
        for (int q = 0; q < 4; ++q) {
            const int row = rt * 16 + ((l >> 4) << 2) + q;
            const float lim = rowm[row] + THR;
            #pragma unroll
            for (int c = 0; c < 8; ++c) {
                if (acc[rt][c][q] <= lim) {
                    const unsigned pos = atomicAdd(&ccnt[row], 1u);
                    if (pos < 8) clist[row * 8 + pos] = (wv * 8 + c) * 16 + (l & 15);
                }
            }
        }
    }
    __syncthreads();

    // ---- exact fallback for rows with >=2 candidates (ref fl order) ----
    if (tid < 256) {
        const int r = tid >> 3, ci = tid & 7;
        const unsigned cc = ccnt[r];
        if (cc >= 2u) {
            if (cc <= 8u) {
                if ((unsigned)ci < cc)
                    fv[r * 8 + ci] = exact_dist(xs, wsC, asum, w, r, clist[r * 8 + ci]);
            } else {
                // PARALLEL safety net: 8 threads x 128-k partitions, local first-min
                float bvv = 3.4e38f; int bkk = ci * 128;
                for (int k = ci * 128; k < ci * 128 + 128; ++k) {
                    const float dvv = exact_dist(xs, wsC, asum, w, r, k);
                    if (dvv < bvv) { bvv = dvv; bkk = k; }
                }
                fv[r * 8 + ci] = bvv;
                clist[r * 8 + ci] = bkk;
            }
        }
    }
    __syncthreads();
    if (tid < 32) {
        const unsigned cc = ccnt[tid];
        int kk;
        if (cc == 1u) kk = clist[tid * 8];
        else {
            const unsigned ncand = (cc <= 8u) ? cc : 8u;   // >8: 8 partition minima
            float v = fv[tid * 8]; kk = clist[tid * 8];
            for (unsigned ci = 1; ci < ncand; ++ci) {
                const float ov = fv[tid * 8 + ci];
                const int   ok = clist[tid * 8 + ci];
                if (ov < v || (ov == v && ok < kk)) { v = ov; kk = ok; }
            }
        }
        bi[tid] = kk;
        __builtin_nontemporal_store((float)kk, &out[OFF_IND + n0 + tid]);
        atomicAdd(&cnt[kk], 1u);
    }
    __syncthreads();

    // ---- z_q straight-through: f32x2 stores ----
    {
        float* zq_out = out + OFF_ZQ + (size_t)b * (DD * HW) + hw0;
        #pragma unroll
        for (int it = 0; it < 8; ++it) {
            const int u = it * 512 + tid;     // 0..4095 f32x2 units: 256 d x 16 pairs
            const int d = u >> 4, j2 = (u & 15) * 2;
            const float la0 = xs[(j2 + 0) * XS_STRIDE + d];
            const float la1 = xs[(j2 + 1) * XS_STRIDE + d];
            const float z0  = w[bi[j2 + 0] * DD + d];
            const float z1  = w[bi[j2 + 1] * DD + d];
            f32x2 v;
            v.x = la0 + (z0 - la0);           // fl(lat + fl(zq - lat))
            v.y = la1 + (z1 - la1);
            __builtin_nontemporal_store(v, reinterpret_cast<f32x2*>(zq_out + d * HW + j2));
        }
    }

    // ---- min_embed one-hot rows (nontemporal f32x2; OFF_EMB only 8B-aligned) ----
    {
        f32x2* emb2 = reinterpret_cast<f32x2*>(out + OFF_EMB) + (size_t)n0 * (KN / 2);
        #pragma unroll
        for (int it = 0; it < 32; ++it) {
            const int f = it * 512 + tid;     // [0, 16384) float2 slots
            const int r = f >> 9;             // 512 float2 per row
            const int kq = (f & 511) * 2;
            const int tt = bi[r];
            f32x2 v2;
            v2.x = (kq     == tt) ? 1.0f : 0.0f;
            v2.y = (kq + 1 == tt) ? 1.0f : 0.0f;
            __builtin_nontemporal_store(v2, &emb2[f]);
        }
    }

    // ---- loss: bit-exact 256-thread replica (store-free; same dif bits) ----
    #pragma unroll
    for (int h = 0; h < 2; ++h) {
        if (tid < 256) {
            const int jj = tid & 15, db = tid >> 4;
            const int krow = bi[h * 16 + jj];
            float lsum = 0.f;
            #pragma unroll
            for (int it = 0; it < 16; ++it) {
                const int d = it * 16 + db;
                const float latv = xs[(h * 16 + jj) * XS_STRIDE + d];
                const float zq   = w[krow * DD + d];
                const float dif  = zq - latv;            // fl(zq - lat)
                lsum = fmaf(dif, dif, lsum);
            }
            float s2 = lsum;
            #pragma unroll
            for (int off = 32; off; off >>= 1) s2 += __shfl_down(s2, off, 64);
            if ((tid & 63) == 0) lred[wv] = (double)s2;
        }
        __syncthreads();
        if (tid == 0) {
            double t = (lred[0] + lred[1]) + (lred[2] + lred[3]);
            atomicAdd(lossSum, t);
        }
        __syncthreads();
    }
}

__global__ __launch_bounds__(1024) void vq_finalize(const unsigned* __restrict__ cnt,
                                                    const double* __restrict__ lossSum,
                                                    float* __restrict__ out) {
    const int t = threadIdx.x;
    __shared__ float red[16];
    const float e = (float)cnt[t] * (1.0f / 32768.0f);
    float s = e * logf(e + 1e-10f);
    #pragma unroll
    for (int off = 32; off; off >>= 1) s += __shfl_down(s, off, 64);
    const int wave = t >> 6, lane = t & 63;
    if (lane == 0) red[wave] = s;
    __syncthreads();
    if (t == 0) {
        float tot = 0.f;
        #pragma unroll
        for (int i = 0; i < 16; ++i) tot += red[i];
        out[OFF_PERP] = expf(-tot);
        const float m = (float)(lossSum[0] * (1.0 / 8388608.0));
        out[OFF_LOSS] = m + 0.25f * m;   // matches fl(m1 + fl(0.25*m2)), m1==m2
    }
}

extern "C" void kernel_launch(void* const* d_in, const int* in_sizes, int n_in,
                              void* d_out, int out_size, void* d_ws, size_t ws_size,
                              hipStream_t stream) {
    const float* lat = (const float*)d_in[0];   // [32,256,32,32] f32 NCHW
    const float* w   = (const float*)d_in[1];   // [1024,256] f32

    char* ws = (char*)d_ws;
    double*   lossSum = (double*)ws;
    unsigned* cnt     = (unsigned*)(ws + 8);
    float*    wsum2   = (float*)(ws + WS_WSUM2_OFF);
    ushort_t* wBh     = (ushort_t*)(ws + WS_WBH_OFF);
    ushort_t* wBl     = (ushort_t*)(ws + WS_WBL_OFF);
    float*    out     = (float*)d_out;

    // zero loss accumulator + histogram every call (we accumulate into them)
    (void)hipMemsetAsync(d_ws, 0, 4104, stream);

    // allow >64KB dynamic LDS for vq_main (not a stream op; graph-capture safe)
    (void)hipFuncSetAttribute(reinterpret_cast<const void*>(vq_main),
                              hipFuncAttributeMaxDynamicSharedMemorySize, SM_SIZE);

    vq_prep<<<KN, 256, 0, stream>>>(w, wsum2, wBh, wBl);
    vq_main<<<NTOT / 32, 512, SM_SIZE, stream>>>(lat, w, wsum2, wBh, wBl, out, cnt, lossSum);
    vq_finalize<<<1, 1024, 0, stream>>>(cnt, lossSum, out);
}